// Round 11
// baseline (606.817 us; speedup 1.0000x reference)
//
#include <hip/hip_runtime.h>

#define NN 50000     // nodes
#define NE 800000    // edges per metapath
#define NP 4         // metapaths
#define DIN 256      // in_size
#define DD 256       // out dim
#define NH 128       // semantic attention hidden
#define SA 40        // LDS row stride in bf16 elems (80 B) — measured conflict-free, keep
#define NSEG 16      // edge segments
#define SEGE (NE / NSEG)   // 50000 edges per segment
#define HCH 32768    // hist/scatter key chunk (128 KB LDS)
#define NHC 2        // 2 * 32768 = 65536 >= NN
#define SCH 8192     // scan key chunk
#define NSC 7        // 7 * 8192 = 57344 >= NN
#define SPAD(k) ((k) + ((k) >> 5))

typedef __attribute__((ext_vector_type(8))) short bf16x8;
typedef __attribute__((ext_vector_type(4))) float f32x4;
typedef __attribute__((ext_vector_type(2))) float f32x2;

__device__ __forceinline__ unsigned short f2bf(float f) {
  unsigned u = __float_as_uint(f);
  u += 0x7fff + ((u >> 16) & 1);  // RNE
  return (unsigned short)(u >> 16);
}
__device__ __forceinline__ float bfl(unsigned u) { return __uint_as_float(u << 16); }
__device__ __forceinline__ float bfh(unsigned u) { return __uint_as_float(u & 0xffff0000u); }

// ---------------- stage 1: 2D histogram cnt[p][s][k], 128 KB LDS counters -----------------
// z=0: src -> cntS, z=1: dst -> cntD. Counts fit ushort (<= SEGE < 2^16).

__global__ __launch_bounds__(256) void histX_kernel(const int* __restrict__ src,
                                                    const int* __restrict__ dst,
                                                    ushort* __restrict__ cntS,
                                                    ushort* __restrict__ cntD) {
  __shared__ int hs[HCH];
  int bx = blockIdx.x;  // c + NHC*s
  int c = bx % NHC, s = bx / NHC;
  int p = blockIdx.y;
  const int* idx = blockIdx.z ? dst : src;
  ushort* cnt = blockIdx.z ? cntD : cntS;
  int base = c * HCH, nk = min(HCH, NN - base);
  for (int k = threadIdx.x; k < HCH; k += 256) hs[k] = 0;
  __syncthreads();
  const int4* a4 = (const int4*)(idx + (size_t)p * NE + (size_t)s * SEGE);
  for (int i = threadIdx.x; i < SEGE / 4; i += 256) {
    int4 v = a4[i];
    int k;
    k = v.x - base; if ((unsigned)k < (unsigned)nk) atomicAdd(&hs[k], 1);
    k = v.y - base; if ((unsigned)k < (unsigned)nk) atomicAdd(&hs[k], 1);
    k = v.z - base; if ((unsigned)k < (unsigned)nk) atomicAdd(&hs[k], 1);
    k = v.w - base; if ((unsigned)k < (unsigned)nk) atomicAdd(&hs[k], 1);
  }
  __syncthreads();
  ushort* out = cnt + (size_t)(p * NSEG + s) * NN + base;
  for (int k = threadIdx.x; k < nk; k += 256) out[k] = (ushort)hs[k];
}

// ---------------- stage 2: per-key seg-prefix (in place), deg->rin/rout, local row_ptr ----

__global__ __launch_bounds__(1024) void scanA_kernel(
    ushort* __restrict__ cntD, const ushort* __restrict__ cntS,
    float* __restrict__ rin, float* __restrict__ rout,
    int* __restrict__ row_ptr, int* __restrict__ chunkdeg) {
  int c = blockIdx.x, p = blockIdx.y;
  int base = c * SCH, nk = min(SCH, NN - base);
  __shared__ int sdeg[SCH + (SCH >> 5)];
  __shared__ int wtot[16], wexc[16];
  int t = threadIdx.x;
  for (int kk = t; kk < SCH; kk += 1024) {
    int run = 0;
    if (kk < nk) {
      size_t o = (size_t)(p * NSEG) * NN + base + kk;
      int vD[NSEG], vS[NSEG];
#pragma unroll
      for (int s = 0; s < NSEG; ++s) vD[s] = cntD[o + (size_t)s * NN];
#pragma unroll
      for (int s = 0; s < NSEG; ++s) vS[s] = cntS[o + (size_t)s * NN];
#pragma unroll
      for (int s = 0; s < NSEG; ++s) {
        cntD[o + (size_t)s * NN] = (ushort)run;
        run += vD[s];
      }
      int rs = 0;
#pragma unroll
      for (int s = 0; s < NSEG; ++s) rs += vS[s];
      rin[(size_t)p * NN + base + kk] = rsqrtf((float)max(run, 1));
      rout[(size_t)p * NN + base + kk] = rsqrtf((float)max(rs, 1));
    }
    sdeg[SPAD(kk)] = run;
  }
  __syncthreads();
  // block exclusive scan over SCH keys; thread t owns keys [t*8, t*8+8)
  int loc[8];
  int ssum = 0;
#pragma unroll
  for (int j = 0; j < 8; ++j) { loc[j] = ssum; ssum += sdeg[SPAD(t * 8 + j)]; }
  int incl = ssum;
  int lane = t & 63, w = t >> 6;
#pragma unroll
  for (int o = 1; o < 64; o <<= 1) {
    int v = __shfl_up(incl, o);
    if (lane >= o) incl += v;
  }
  if (lane == 63) wtot[w] = incl;
  __syncthreads();
  if (t == 0) {
    int r = 0;
    for (int i = 0; i < 16; ++i) { wexc[i] = r; r += wtot[i]; }
  }
  __syncthreads();
  int tbase = wexc[w] + incl - ssum;
  int* rp = row_ptr + (size_t)p * (NN + 1) + base;
#pragma unroll
  for (int j = 0; j < 8; ++j) {
    int k = t * 8 + j;
    if (k < nk) rp[k] = tbase + loc[j];
  }
  if (t == 1023) chunkdeg[p * NSC + c] = tbase + ssum;
}

// ---------------- stage 3: cross-chunk bases ----------------

__global__ __launch_bounds__(1024) void rpfin_kernel(int* __restrict__ row_ptr,
                                                     const int* __restrict__ chunkdeg) {
  int k = blockIdx.x * 1024 + threadIdx.x, p = blockIdx.y;
  if (k < NN) {
    int c = k >> 13;  // SCH = 8192
    int cb = 0;
    for (int i = 0; i < c; ++i) cb += chunkdeg[p * NSC + i];
    row_ptr[(size_t)p * (NN + 1) + k] += cb;
  }
  if (k == 0) row_ptr[(size_t)p * (NN + 1) + NN] = NE;
}

// ---------------- stage 4: scatter col with 128 KB LDS cursors ----------------

__global__ __launch_bounds__(256) void scatter_kernel(
    const int* __restrict__ src, const int* __restrict__ dst,
    const ushort* __restrict__ cntD, const int* __restrict__ row_ptr, int* __restrict__ col) {
  __shared__ int cur[HCH];
  int bx = blockIdx.x;
  int c = bx % NHC, s = bx / NHC;
  int p = blockIdx.y;
  int base = c * HCH, nk = min(HCH, NN - base);
  for (int k = threadIdx.x; k < nk; k += 256)
    cur[k] = row_ptr[(size_t)p * (NN + 1) + base + k] +
             cntD[(size_t)(p * NSEG + s) * NN + base + k];
  __syncthreads();
  const int4* d4 = (const int4*)(dst + (size_t)p * NE + (size_t)s * SEGE);
  const int4* s4 = (const int4*)(src + (size_t)p * NE + (size_t)s * SEGE);
  int* colp = col + (size_t)p * NE;
  for (int i = threadIdx.x; i < SEGE / 4; i += 256) {
    int4 dv = d4[i];
    int4 sv = s4[i];
    int k;
    k = dv.x - base; if ((unsigned)k < (unsigned)nk) colp[atomicAdd(&cur[k], 1)] = sv.x;
    k = dv.y - base; if ((unsigned)k < (unsigned)nk) colp[atomicAdd(&cur[k], 1)] = sv.y;
    k = dv.z - base; if ((unsigned)k < (unsigned)nk) colp[atomicAdd(&cur[k], 1)] = sv.z;
    k = dv.w - base; if ((unsigned)k < (unsigned)nk) colp[atomicAdd(&cur[k], 1)] = sv.w;
  }
}

// ---------------- h -> bf16 ----------------

__global__ void cvt_h_kernel(const float4* __restrict__ h4, ushort4* __restrict__ h2) {
  int i = blockIdx.x * blockDim.x + threadIdx.x;
  if (i >= NN * DIN / 4) return;
  float4 v = h4[i];
  ushort4 o;
  o.x = f2bf(v.x); o.y = f2bf(v.y); o.z = f2bf(v.z); o.w = f2bf(v.w);
  h2[i] = o;
}

// ---------------- aggregation: g_p = rin * sum_src rout[src] * h2[src] (bf16 out) ----------
// One wave per node (round-2 verified version; ~4 TB/s CU-path cap — do not re-tune).
// pbase selects the metapath; 4 single-path dispatches purely for rocprof top-5 visibility.

__global__ __launch_bounds__(256) void agg_kernel(
    const ushort* __restrict__ h2, const int* __restrict__ col,
    const int* __restrict__ row_ptr, const float* __restrict__ rout,
    const float* __restrict__ rin, ushort* __restrict__ g, int pbase) {
  __shared__ int2 sW[4][64];
  int p = pbase + blockIdx.y;
  int v = blockIdx.x * 4 + (threadIdx.x >> 6);
  int lane = threadIdx.x & 63;
  int wv = threadIdx.x >> 6;
  const int* colp = col + (size_t)p * NE;
  const float* rop = rout + (size_t)p * NN;
  int beg = row_ptr[p * (NN + 1) + v], end = row_ptr[p * (NN + 1) + v + 1];
  const char* hb = (const char*)h2 + (size_t)lane * 8;  // this lane's 8B slice of a row
  f32x2 accA0 = {0.f, 0.f}, accA1 = {0.f, 0.f};
  f32x2 accB0 = {0.f, 0.f}, accB1 = {0.f, 0.f};
  for (int j0 = beg; j0 < end; j0 += 64) {
    int nw = end - j0;
    if (nw > 64) nw = 64;
    int cv = 0;
    float rv = 0.f;
    if (lane < nw) { cv = colp[j0 + lane]; rv = rop[cv]; }
    sW[wv][lane] = make_int2(cv, __float_as_int(rv));
    int nwb = (nw + 7) & ~7;
    for (int t = 0; t < nwb; t += 8) {
      int2 w[8];
#pragma unroll
      for (int q = 0; q < 8; ++q) w[q] = sW[wv][t + q];
      uint2 u[8];
#pragma unroll
      for (int q = 0; q < 8; ++q)
        u[q] = *(const uint2*)(hb + ((size_t)(unsigned)w[q].x << 9));
#pragma unroll
      for (int q = 0; q < 8; ++q) {
        float r = __int_as_float(w[q].y);
        f32x2 rr = {r, r};
        if (q & 1) {
          asm("v_pk_fma_f32 %0, %1, %2, %0" : "+v"(accB0) : "v"(rr), "v"((f32x2){bfl(u[q].x), bfh(u[q].x)}));
          asm("v_pk_fma_f32 %0, %1, %2, %0" : "+v"(accB1) : "v"(rr), "v"((f32x2){bfl(u[q].y), bfh(u[q].y)}));
        } else {
          asm("v_pk_fma_f32 %0, %1, %2, %0" : "+v"(accA0) : "v"(rr), "v"((f32x2){bfl(u[q].x), bfh(u[q].x)}));
          asm("v_pk_fma_f32 %0, %1, %2, %0" : "+v"(accA1) : "v"(rr), "v"((f32x2){bfl(u[q].y), bfh(u[q].y)}));
        }
      }
    }
  }
  float ri = rin[(size_t)p * NN + v];
  f32x2 s0 = accA0 + accB0;
  f32x2 s1 = accA1 + accB1;
  ushort4 o;
  o.x = f2bf(s0.x * ri); o.y = f2bf(s0.y * ri);
  o.z = f2bf(s1.x * ri); o.w = f2bf(s1.y * ri);
  ((ushort4*)(g + ((size_t)p * NN + v) * DIN))[lane] = o;
}

// ---------------- Mt_p = (W_p @ W1)^T (bf16, n-major) + c_p = b_p @ W1 + b1 (fused) --------

__global__ void wmulcvec_kernel(const float* __restrict__ Wgc, const float* __restrict__ bgc,
                                const float* __restrict__ W1, const float* __restrict__ b1,
                                ushort* __restrict__ Mt, float* __restrict__ cvec) {
  int p = blockIdx.y, k = blockIdx.x, j = threadIdx.x;  // block = 128
  if (k < DIN) {
    const float* wrow = Wgc + ((size_t)p * DIN + k) * DD;
    float s = 0.f;
    for (int d = 0; d < DD; ++d) s = fmaf(wrow[d], W1[(size_t)d * NH + j], s);
    Mt[((size_t)p * NH + j) * DIN + k] = f2bf(s);
  } else {
    const float* b = bgc + (size_t)p * DD;
    float s = b1[j];
    for (int d = 0; d < DD; ++d) s = fmaf(b[d], W1[(size_t)d * NH + j], s);
    cvec[p * NH + j] = s;
  }
}

// ---------------- gemm_sem: ssum[p] = sum_{n,c} tanh(g_p @ M_p + c)[n,c] * w2[c] --------
// BK=32 / SA=40 (measured conflict-free) — round-8 verified version.

__global__ __launch_bounds__(256) void gemm_sem(
    const ushort* __restrict__ g, const ushort* __restrict__ Mt,
    const float* __restrict__ cvec, const float* __restrict__ w2,
    float* __restrict__ ssum) {
  __shared__ ushort As[128 * SA];
  __shared__ ushort Bs[128 * SA];
  __shared__ float wsumf[4];
  const int tid = threadIdx.x;
  const int p = blockIdx.y;
  const int row0 = blockIdx.x * 128;
  const int wave = tid >> 6, lane = tid & 63;
  const int wr = wave >> 1, wc = wave & 1;
  const int srow = tid >> 2, sseg = tid & 3;
  const int fr = lane & 15, fk = (lane >> 4) * 8;
  const ushort* Ag = g + (size_t)p * NN * DIN;
  const ushort* Bg = Mt + (size_t)p * NH * DIN;
  int ar0 = row0 + srow; if (ar0 >= NN) ar0 = NN - 1;
  int ar1 = row0 + srow + 64; if (ar1 >= NN) ar1 = NN - 1;
  f32x4 acc[4][4] = {};
  for (int k2 = 0; k2 < DIN; k2 += 32) {
    uint4 av0 = *(const uint4*)(Ag + (size_t)ar0 * DIN + k2 + sseg * 8);
    uint4 av1 = *(const uint4*)(Ag + (size_t)ar1 * DIN + k2 + sseg * 8);
    uint4 bv0 = *(const uint4*)(Bg + (size_t)srow * DIN + k2 + sseg * 8);
    uint4 bv1 = *(const uint4*)(Bg + (size_t)(srow + 64) * DIN + k2 + sseg * 8);
    __syncthreads();
    *(uint4*)&As[srow * SA + sseg * 8] = av0;
    *(uint4*)&As[(srow + 64) * SA + sseg * 8] = av1;
    *(uint4*)&Bs[srow * SA + sseg * 8] = bv0;
    *(uint4*)&Bs[(srow + 64) * SA + sseg * 8] = bv1;
    __syncthreads();
    bf16x8 af[4], bfv[4];
#pragma unroll
    for (int t = 0; t < 4; ++t) {
      af[t] = *(const bf16x8*)&As[(wr * 64 + t * 16 + fr) * SA + fk];
      bfv[t] = *(const bf16x8*)&Bs[(wc * 64 + t * 16 + fr) * SA + fk];
    }
#pragma unroll
    for (int mt = 0; mt < 4; ++mt)
#pragma unroll
      for (int nt = 0; nt < 4; ++nt)
        acc[mt][nt] = __builtin_amdgcn_mfma_f32_16x16x32_bf16(af[mt], bfv[nt], acc[mt][nt], 0, 0, 0);
  }
  float s = 0.f;
#pragma unroll
  for (int nt = 0; nt < 4; ++nt) {
    int c = wc * 64 + nt * 16 + fr;
    float cc = cvec[p * NH + c];
    float ww = w2[c];
#pragma unroll
    for (int mt = 0; mt < 4; ++mt)
#pragma unroll
      for (int i = 0; i < 4; ++i) {
        int r = row0 + wr * 64 + mt * 16 + (lane >> 4) * 4 + i;
        if (r < NN) {
          float x = acc[mt][nt][i] + cc;
          x = fminf(fmaxf(x, -15.f), 15.f);
          float e = __expf(2.f * x);
          s = fmaf((e - 1.f) / (e + 1.f), ww, s);
        }
      }
  }
#pragma unroll
  for (int o = 32; o > 0; o >>= 1) s += __shfl_down(s, o);
  if (lane == 0) wsumf[wave] = s;
  __syncthreads();
  if (tid == 0) atomicAdd(&ssum[p], wsumf[0] + wsumf[1] + wsumf[2] + wsumf[3]);
}

// ---------------- beta (inline per-thread) + beta-scaled W^T (bf16) + bout ----------------

__global__ __launch_bounds__(256) void scaleWtB_kernel(const float* __restrict__ Wgc,
                                                       const float* __restrict__ ssum,
                                                       const float* __restrict__ bgc,
                                                       ushort* __restrict__ Wt,
                                                       float* __restrict__ bout) {
  float m[NP];
  float mx = -1e30f;
#pragma unroll
  for (int p = 0; p < NP; ++p) {
    m[p] = ssum[p] * (1.f / (float)NN);
    mx = fmaxf(mx, m[p]);
  }
  float tot = 0.f;
#pragma unroll
  for (int p = 0; p < NP; ++p) { m[p] = __expf(m[p] - mx); tot += m[p]; }
  float inv = 1.f / tot;
  if (blockIdx.x == 0) {
    int d = threadIdx.x;  // block = 256 = DD
    float s = 0.f;
#pragma unroll
    for (int p = 0; p < NP; ++p) s = fmaf(m[p] * inv, bgc[p * DD + d], s);
    bout[d] = s;
  }
  int i = blockIdx.x * 256 + threadIdx.x;  // over DD * NP * DIN
  if (i < DD * NP * DIN) {
    int n = i >> 10;
    int pk = i & 1023;
    int p = pk >> 8, k = pk & 255;
    Wt[i] = f2bf(m[p] * inv * Wgc[((size_t)p * DIN + k) * DD + n]);
  }
}

// ---------------- gemm_main: out = [g_0|..|g_3] @ Wt^T + bout ----------------
// BK=32 / SA=40 (measured conflict-free), 128x256 tile — round-8 verified version.

__global__ __launch_bounds__(256) void gemm_main(
    const ushort* __restrict__ g, const ushort* __restrict__ Wt,
    const float* __restrict__ bout, float* __restrict__ out) {
  __shared__ ushort As[128 * SA];
  __shared__ ushort Bs[256 * SA];
  const int tid = threadIdx.x;
  const int row0 = blockIdx.x * 128;
  const int wave = tid >> 6, lane = tid & 63;
  const int wr = wave >> 1, wc = wave & 1;
  const int srow = tid >> 2, sseg = tid & 3;
  const int fr = lane & 15, fk = (lane >> 4) * 8;
  int ar0 = row0 + srow; if (ar0 >= NN) ar0 = NN - 1;
  int ar1 = row0 + srow + 64; if (ar1 >= NN) ar1 = NN - 1;
  f32x4 acc[4][8] = {};
  for (int p = 0; p < NP; ++p) {
    const ushort* Ag = g + (size_t)p * NN * DIN;
    for (int k2 = 0; k2 < DIN; k2 += 32) {
      uint4 av0 = *(const uint4*)(Ag + (size_t)ar0 * DIN + k2 + sseg * 8);
      uint4 av1 = *(const uint4*)(Ag + (size_t)ar1 * DIN + k2 + sseg * 8);
      uint4 bv0 = *(const uint4*)(Wt + (size_t)srow * (NP * DIN) + p * DIN + k2 + sseg * 8);
      uint4 bv1 = *(const uint4*)(Wt + (size_t)(srow + 64) * (NP * DIN) + p * DIN + k2 + sseg * 8);
      uint4 bv2 = *(const uint4*)(Wt + (size_t)(srow + 128) * (NP * DIN) + p * DIN + k2 + sseg * 8);
      uint4 bv3 = *(const uint4*)(Wt + (size_t)(srow + 192) * (NP * DIN) + p * DIN + k2 + sseg * 8);
      __syncthreads();
      *(uint4*)&As[srow * SA + sseg * 8] = av0;
      *(uint4*)&As[(srow + 64) * SA + sseg * 8] = av1;
      *(uint4*)&Bs[srow * SA + sseg * 8] = bv0;
      *(uint4*)&Bs[(srow + 64) * SA + sseg * 8] = bv1;
      *(uint4*)&Bs[(srow + 128) * SA + sseg * 8] = bv2;
      *(uint4*)&Bs[(srow + 192) * SA + sseg * 8] = bv3;
      __syncthreads();
      bf16x8 af[4], bfv[8];
#pragma unroll
      for (int t = 0; t < 4; ++t)
        af[t] = *(const bf16x8*)&As[(wr * 64 + t * 16 + fr) * SA + fk];
#pragma unroll
      for (int nt = 0; nt < 8; ++nt)
        bfv[nt] = *(const bf16x8*)&Bs[(wc * 128 + nt * 16 + fr) * SA + fk];
#pragma unroll
      for (int mt = 0; mt < 4; ++mt)
#pragma unroll
        for (int nt = 0; nt < 8; ++nt)
          acc[mt][nt] = __builtin_amdgcn_mfma_f32_16x16x32_bf16(af[mt], bfv[nt], acc[mt][nt], 0, 0, 0);
    }
  }
#pragma unroll
  for (int nt = 0; nt < 8; ++nt) {
    int c = wc * 128 + nt * 16 + fr;
    float bb = bout[c];
#pragma unroll
    for (int mt = 0; mt < 4; ++mt)
#pragma unroll
      for (int i = 0; i < 4; ++i) {
        int r = row0 + wr * 64 + mt * 16 + (lane >> 4) * 4 + i;
        if (r < NN) out[(size_t)r * DD + c] = acc[mt][nt][i] + bb;
      }
  }
}

// ---------------- launcher ----------------

extern "C" void kernel_launch(void* const* d_in, const int* in_sizes, int n_in,
                              void* d_out, int out_size, void* d_ws, size_t ws_size,
                              hipStream_t stream) {
  const float* h = (const float*)d_in[0];
  const int* src = (const int*)d_in[1];
  const int* dst = (const int*)d_in[2];
  const float* Wgc = (const float*)d_in[3];
  const float* bgc = (const float*)d_in[4];
  const float* W1 = (const float*)d_in[5];
  const float* b1 = (const float*)d_in[6];
  const float* w2 = (const float*)d_in[7];
  float* out = (float*)d_out;

  char* base = (char*)d_ws;
  size_t off = 0;
  auto alloc = [&](size_t bytes) -> char* {
    char* ptr = base + off;
    off = (off + bytes + 255) & ~(size_t)255;
    return ptr;
  };
  ushort* cntD = (ushort*)alloc((size_t)NP * NSEG * NN * sizeof(ushort));
  ushort* cntS = (ushort*)alloc((size_t)NP * NSEG * NN * sizeof(ushort));
  float* rin = (float*)alloc((size_t)NP * NN * sizeof(float));
  float* rout = (float*)alloc((size_t)NP * NN * sizeof(float));
  int* row_ptr = (int*)alloc((size_t)NP * (NN + 1) * sizeof(int));
  int* chunkdeg = (int*)alloc((size_t)NP * NSC * sizeof(int));
  int* colbuf = (int*)alloc((size_t)NP * NE * sizeof(int));
  ushort* h2 = (ushort*)alloc((size_t)NN * DIN * sizeof(ushort));
  ushort* g = (ushort*)alloc((size_t)NP * NN * DIN * sizeof(ushort));
  ushort* Mt = (ushort*)alloc((size_t)NP * NH * DIN * sizeof(ushort));
  ushort* Wt = (ushort*)alloc((size_t)DD * NP * DIN * sizeof(ushort));
  float* cvec = (float*)alloc((size_t)NP * NH * sizeof(float));
  float* ssum = (float*)alloc(NP * sizeof(float));
  float* bout = (float*)alloc(DD * sizeof(float));
  if (off > ws_size) return;

  hipMemsetAsync(ssum, 0, NP * sizeof(float), stream);

  histX_kernel<<<dim3(NHC * NSEG, NP, 2), 256, 0, stream>>>(src, dst, cntS, cntD);
  scanA_kernel<<<dim3(NSC, NP), 1024, 0, stream>>>(cntD, cntS, rin, rout, row_ptr, chunkdeg);
  rpfin_kernel<<<dim3((NN + 1023) / 1024, NP), 1024, 0, stream>>>(row_ptr, chunkdeg);
  cvt_h_kernel<<<(NN * DIN / 4 + 255) / 256, 256, 0, stream>>>((const float4*)h, (ushort4*)h2);
  scatter_kernel<<<dim3(NHC * NSEG, NP), 256, 0, stream>>>(src, dst, cntD, row_ptr, colbuf);
  agg_kernel<<<dim3(NN / 4, 1), 256, 0, stream>>>(h2, colbuf, row_ptr, rout, rin, g, 0);
  agg_kernel<<<dim3(NN / 4, 1), 256, 0, stream>>>(h2, colbuf, row_ptr, rout, rin, g, 1);
  agg_kernel<<<dim3(NN / 4, 1), 256, 0, stream>>>(h2, colbuf, row_ptr, rout, rin, g, 2);
  agg_kernel<<<dim3(NN / 4, 1), 256, 0, stream>>>(h2, colbuf, row_ptr, rout, rin, g, 3);
  wmulcvec_kernel<<<dim3(DIN + 1, NP), NH, 0, stream>>>(Wgc, bgc, W1, b1, Mt, cvec);
  gemm_sem<<<dim3((NN + 127) / 128, NP), 256, 0, stream>>>(g, Mt, cvec, w2, ssum);
  scaleWtB_kernel<<<(DD * NP * DIN + 255) / 256, 256, 0, stream>>>(Wgc, ssum, bgc, Wt, bout);
  gemm_main<<<dim3((NN + 127) / 128), 256, 0, stream>>>(g, Wt, bout, out);
}

// Round 12
// 574.984 us; speedup vs baseline: 1.0554x; 1.0554x over previous
//
#include <hip/hip_runtime.h>

#define NN 50000     // nodes
#define NE 800000    // edges per metapath
#define NP 4         // metapaths
#define DIN 256      // in_size
#define DD 256       // out dim
#define NH 128       // semantic attention hidden
#define SA 40        // LDS row stride in bf16 elems (80 B)
#define NSEG 16      // edge segments
#define SEGE (NE / NSEG)   // 50000 edges per segment
#define HCH 32768    // hist/scatter key chunk (128 KB LDS)
#define NHC 2        // 2 * 32768 = 65536 >= NN
#define SCH 8192     // scan key chunk
#define NSC 7        // 7 * 8192 = 57344 >= NN
#define SPAD(k) ((k) + ((k) >> 5))

typedef __attribute__((ext_vector_type(8))) short bf16x8;
typedef __attribute__((ext_vector_type(4))) float f32x4;
typedef __attribute__((ext_vector_type(2))) float f32x2;

__device__ __forceinline__ unsigned short f2bf(float f) {
  unsigned u = __float_as_uint(f);
  u += 0x7fff + ((u >> 16) & 1);  // RNE
  return (unsigned short)(u >> 16);
}
__device__ __forceinline__ float bfl(unsigned u) { return __uint_as_float(u << 16); }
__device__ __forceinline__ float bfh(unsigned u) { return __uint_as_float(u & 0xffff0000u); }

// ---------------- stage 1: 2D histogram cnt[p][s][k], 128 KB LDS counters -----------------
// z=0: src -> cntS, z=1: dst -> cntD. Counts fit ushort (<= SEGE < 2^16).

__global__ __launch_bounds__(256) void histX_kernel(const int* __restrict__ src,
                                                    const int* __restrict__ dst,
                                                    ushort* __restrict__ cntS,
                                                    ushort* __restrict__ cntD) {
  __shared__ int hs[HCH];
  int bx = blockIdx.x;  // c + NHC*s
  int c = bx % NHC, s = bx / NHC;
  int p = blockIdx.y;
  const int* idx = blockIdx.z ? dst : src;
  ushort* cnt = blockIdx.z ? cntD : cntS;
  int base = c * HCH, nk = min(HCH, NN - base);
  for (int k = threadIdx.x; k < HCH; k += 256) hs[k] = 0;
  __syncthreads();
  const int4* a4 = (const int4*)(idx + (size_t)p * NE + (size_t)s * SEGE);
  for (int i = threadIdx.x; i < SEGE / 4; i += 256) {
    int4 v = a4[i];
    int k;
    k = v.x - base; if ((unsigned)k < (unsigned)nk) atomicAdd(&hs[k], 1);
    k = v.y - base; if ((unsigned)k < (unsigned)nk) atomicAdd(&hs[k], 1);
    k = v.z - base; if ((unsigned)k < (unsigned)nk) atomicAdd(&hs[k], 1);
    k = v.w - base; if ((unsigned)k < (unsigned)nk) atomicAdd(&hs[k], 1);
  }
  __syncthreads();
  ushort* out = cnt + (size_t)(p * NSEG + s) * NN + base;
  for (int k = threadIdx.x; k < nk; k += 256) out[k] = (ushort)hs[k];
}

// ---------------- stage 2: per-key seg-prefix (in place), deg->rin/rout, local row_ptr ----

__global__ __launch_bounds__(1024) void scanA_kernel(
    ushort* __restrict__ cntD, const ushort* __restrict__ cntS,
    float* __restrict__ rin, float* __restrict__ rout,
    int* __restrict__ row_ptr, int* __restrict__ chunkdeg) {
  int c = blockIdx.x, p = blockIdx.y;
  int base = c * SCH, nk = min(SCH, NN - base);
  __shared__ int sdeg[SCH + (SCH >> 5)];
  __shared__ int wtot[16], wexc[16];
  int t = threadIdx.x;
  for (int kk = t; kk < SCH; kk += 1024) {
    int run = 0;
    if (kk < nk) {
      size_t o = (size_t)(p * NSEG) * NN + base + kk;
      int vD[NSEG], vS[NSEG];
#pragma unroll
      for (int s = 0; s < NSEG; ++s) vD[s] = cntD[o + (size_t)s * NN];
#pragma unroll
      for (int s = 0; s < NSEG; ++s) vS[s] = cntS[o + (size_t)s * NN];
#pragma unroll
      for (int s = 0; s < NSEG; ++s) {
        cntD[o + (size_t)s * NN] = (ushort)run;
        run += vD[s];
      }
      int rs = 0;
#pragma unroll
      for (int s = 0; s < NSEG; ++s) rs += vS[s];
      rin[(size_t)p * NN + base + kk] = rsqrtf((float)max(run, 1));
      rout[(size_t)p * NN + base + kk] = rsqrtf((float)max(rs, 1));
    }
    sdeg[SPAD(kk)] = run;
  }
  __syncthreads();
  // block exclusive scan over SCH keys; thread t owns keys [t*8, t*8+8)
  int loc[8];
  int ssum = 0;
#pragma unroll
  for (int j = 0; j < 8; ++j) { loc[j] = ssum; ssum += sdeg[SPAD(t * 8 + j)]; }
  int incl = ssum;
  int lane = t & 63, w = t >> 6;
#pragma unroll
  for (int o = 1; o < 64; o <<= 1) {
    int v = __shfl_up(incl, o);
    if (lane >= o) incl += v;
  }
  if (lane == 63) wtot[w] = incl;
  __syncthreads();
  if (t == 0) {
    int r = 0;
    for (int i = 0; i < 16; ++i) { wexc[i] = r; r += wtot[i]; }
  }
  __syncthreads();
  int tbase = wexc[w] + incl - ssum;
  int* rp = row_ptr + (size_t)p * (NN + 1) + base;
#pragma unroll
  for (int j = 0; j < 8; ++j) {
    int k = t * 8 + j;
    if (k < nk) rp[k] = tbase + loc[j];
  }
  if (t == 1023) chunkdeg[p * NSC + c] = tbase + ssum;
}

// ---------------- stage 3: cross-chunk bases ----------------

__global__ __launch_bounds__(1024) void rpfin_kernel(int* __restrict__ row_ptr,
                                                     const int* __restrict__ chunkdeg) {
  int k = blockIdx.x * 1024 + threadIdx.x, p = blockIdx.y;
  if (k < NN) {
    int c = k >> 13;  // SCH = 8192
    int cb = 0;
    for (int i = 0; i < c; ++i) cb += chunkdeg[p * NSC + i];
    row_ptr[(size_t)p * (NN + 1) + k] += cb;
  }
  if (k == 0) row_ptr[(size_t)p * (NN + 1) + NN] = NE;
}

// ---------------- stage 4: scatter col with 128 KB LDS cursors ----------------

__global__ __launch_bounds__(256) void scatter_kernel(
    const int* __restrict__ src, const int* __restrict__ dst,
    const ushort* __restrict__ cntD, const int* __restrict__ row_ptr, int* __restrict__ col) {
  __shared__ int cur[HCH];
  int bx = blockIdx.x;
  int c = bx % NHC, s = bx / NHC;
  int p = blockIdx.y;
  int base = c * HCH, nk = min(HCH, NN - base);
  for (int k = threadIdx.x; k < nk; k += 256)
    cur[k] = row_ptr[(size_t)p * (NN + 1) + base + k] +
             cntD[(size_t)(p * NSEG + s) * NN + base + k];
  __syncthreads();
  const int4* d4 = (const int4*)(dst + (size_t)p * NE + (size_t)s * SEGE);
  const int4* s4 = (const int4*)(src + (size_t)p * NE + (size_t)s * SEGE);
  int* colp = col + (size_t)p * NE;
  for (int i = threadIdx.x; i < SEGE / 4; i += 256) {
    int4 dv = d4[i];
    int4 sv = s4[i];
    int k;
    k = dv.x - base; if ((unsigned)k < (unsigned)nk) colp[atomicAdd(&cur[k], 1)] = sv.x;
    k = dv.y - base; if ((unsigned)k < (unsigned)nk) colp[atomicAdd(&cur[k], 1)] = sv.y;
    k = dv.z - base; if ((unsigned)k < (unsigned)nk) colp[atomicAdd(&cur[k], 1)] = sv.z;
    k = dv.w - base; if ((unsigned)k < (unsigned)nk) colp[atomicAdd(&cur[k], 1)] = sv.w;
  }
}

// ---------------- h -> bf16 ----------------

__global__ void cvt_h_kernel(const float4* __restrict__ h4, ushort4* __restrict__ h2) {
  int i = blockIdx.x * blockDim.x + threadIdx.x;
  if (i >= NN * DIN / 4) return;
  float4 v = h4[i];
  ushort4 o;
  o.x = f2bf(v.x); o.y = f2bf(v.y); o.z = f2bf(v.z); o.w = f2bf(v.w);
  h2[i] = o;
}

// ---------------- aggregation: g_p = rin * sum_src rout[src] * h2[src] (bf16 out) ----------
// One wave per node (round-2 verified version; ~4 TB/s CU-path cap — do not re-tune).

__global__ __launch_bounds__(256) void agg_kernel(
    const ushort* __restrict__ h2, const int* __restrict__ col,
    const int* __restrict__ row_ptr, const float* __restrict__ rout,
    const float* __restrict__ rin, ushort* __restrict__ g, int pbase) {
  __shared__ int2 sW[4][64];
  int p = pbase + blockIdx.y;
  int v = blockIdx.x * 4 + (threadIdx.x >> 6);
  int lane = threadIdx.x & 63;
  int wv = threadIdx.x >> 6;
  const int* colp = col + (size_t)p * NE;
  const float* rop = rout + (size_t)p * NN;
  int beg = row_ptr[p * (NN + 1) + v], end = row_ptr[p * (NN + 1) + v + 1];
  const char* hb = (const char*)h2 + (size_t)lane * 8;  // this lane's 8B slice of a row
  f32x2 accA0 = {0.f, 0.f}, accA1 = {0.f, 0.f};
  f32x2 accB0 = {0.f, 0.f}, accB1 = {0.f, 0.f};
  for (int j0 = beg; j0 < end; j0 += 64) {
    int nw = end - j0;
    if (nw > 64) nw = 64;
    int cv = 0;
    float rv = 0.f;
    if (lane < nw) { cv = colp[j0 + lane]; rv = rop[cv]; }
    sW[wv][lane] = make_int2(cv, __float_as_int(rv));
    int nwb = (nw + 7) & ~7;
    for (int t = 0; t < nwb; t += 8) {
      int2 w[8];
#pragma unroll
      for (int q = 0; q < 8; ++q) w[q] = sW[wv][t + q];
      uint2 u[8];
#pragma unroll
      for (int q = 0; q < 8; ++q)
        u[q] = *(const uint2*)(hb + ((size_t)(unsigned)w[q].x << 9));
#pragma unroll
      for (int q = 0; q < 8; ++q) {
        float r = __int_as_float(w[q].y);
        f32x2 rr = {r, r};
        if (q & 1) {
          asm("v_pk_fma_f32 %0, %1, %2, %0" : "+v"(accB0) : "v"(rr), "v"((f32x2){bfl(u[q].x), bfh(u[q].x)}));
          asm("v_pk_fma_f32 %0, %1, %2, %0" : "+v"(accB1) : "v"(rr), "v"((f32x2){bfl(u[q].y), bfh(u[q].y)}));
        } else {
          asm("v_pk_fma_f32 %0, %1, %2, %0" : "+v"(accA0) : "v"(rr), "v"((f32x2){bfl(u[q].x), bfh(u[q].x)}));
          asm("v_pk_fma_f32 %0, %1, %2, %0" : "+v"(accA1) : "v"(rr), "v"((f32x2){bfl(u[q].y), bfh(u[q].y)}));
        }
      }
    }
  }
  float ri = rin[(size_t)p * NN + v];
  f32x2 s0 = accA0 + accB0;
  f32x2 s1 = accA1 + accB1;
  ushort4 o;
  o.x = f2bf(s0.x * ri); o.y = f2bf(s0.y * ri);
  o.z = f2bf(s1.x * ri); o.w = f2bf(s1.y * ri);
  ((ushort4*)(g + ((size_t)p * NN + v) * DIN))[lane] = o;
}

// ---------------- Mt_p = (W_p @ W1)^T (bf16, n-major) + c_p = b_p @ W1 + b1 (fused) --------

__global__ void wmulcvec_kernel(const float* __restrict__ Wgc, const float* __restrict__ bgc,
                                const float* __restrict__ W1, const float* __restrict__ b1,
                                ushort* __restrict__ Mt, float* __restrict__ cvec) {
  int p = blockIdx.y, k = blockIdx.x, j = threadIdx.x;  // block = 128
  if (k < DIN) {
    const float* wrow = Wgc + ((size_t)p * DIN + k) * DD;
    float s = 0.f;
    for (int d = 0; d < DD; ++d) s = fmaf(wrow[d], W1[(size_t)d * NH + j], s);
    Mt[((size_t)p * NH + j) * DIN + k] = f2bf(s);
  } else {
    const float* b = bgc + (size_t)p * DD;
    float s = b1[j];
    for (int d = 0; d < DD; ++d) s = fmaf(b[d], W1[(size_t)d * NH + j], s);
    cvec[p * NH + j] = s;
  }
}

// ---------------- gemm_sem: ssum[p] = sum_{n,c} tanh(g_p @ M_p + c)[n,c] * w2[c] --------
// BK=32 / SA=40. Staging rows staggered (srow = ((q&31)<<1)|(q>>5)) so each 16-lane
// quarter writes rows {2i}: bank-quads covered exactly 2x = conflict-free (20 dwords/row;
// the old srow=q pattern had 3-way write conflicts — derived + measured 4.8M in gemm_main).

__global__ __launch_bounds__(256) void gemm_sem(
    const ushort* __restrict__ g, const ushort* __restrict__ Mt,
    const float* __restrict__ cvec, const float* __restrict__ w2,
    float* __restrict__ ssum) {
  __shared__ ushort As[128 * SA];
  __shared__ ushort Bs[128 * SA];
  __shared__ float wsumf[4];
  const int tid = threadIdx.x;
  const int p = blockIdx.y;
  const int row0 = blockIdx.x * 128;
  const int wave = tid >> 6, lane = tid & 63;
  const int wr = wave >> 1, wc = wave & 1;
  const int q = tid >> 2, sseg = tid & 3;
  const int srow = ((q & 31) << 1) | (q >> 5);  // staggered, bijective 0..63
  const int fr = lane & 15, fk = (lane >> 4) * 8;
  const ushort* Ag = g + (size_t)p * NN * DIN;
  const ushort* Bg = Mt + (size_t)p * NH * DIN;
  int ar0 = row0 + srow; if (ar0 >= NN) ar0 = NN - 1;
  int ar1 = row0 + srow + 64; if (ar1 >= NN) ar1 = NN - 1;
  f32x4 acc[4][4] = {};
  for (int k2 = 0; k2 < DIN; k2 += 32) {
    uint4 av0 = *(const uint4*)(Ag + (size_t)ar0 * DIN + k2 + sseg * 8);
    uint4 av1 = *(const uint4*)(Ag + (size_t)ar1 * DIN + k2 + sseg * 8);
    uint4 bv0 = *(const uint4*)(Bg + (size_t)srow * DIN + k2 + sseg * 8);
    uint4 bv1 = *(const uint4*)(Bg + (size_t)(srow + 64) * DIN + k2 + sseg * 8);
    __syncthreads();
    *(uint4*)&As[srow * SA + sseg * 8] = av0;
    *(uint4*)&As[(srow + 64) * SA + sseg * 8] = av1;
    *(uint4*)&Bs[srow * SA + sseg * 8] = bv0;
    *(uint4*)&Bs[(srow + 64) * SA + sseg * 8] = bv1;
    __syncthreads();
    bf16x8 af[4], bfv[4];
#pragma unroll
    for (int t = 0; t < 4; ++t) {
      af[t] = *(const bf16x8*)&As[(wr * 64 + t * 16 + fr) * SA + fk];
      bfv[t] = *(const bf16x8*)&Bs[(wc * 64 + t * 16 + fr) * SA + fk];
    }
#pragma unroll
    for (int mt = 0; mt < 4; ++mt)
#pragma unroll
      for (int nt = 0; nt < 4; ++nt)
        acc[mt][nt] = __builtin_amdgcn_mfma_f32_16x16x32_bf16(af[mt], bfv[nt], acc[mt][nt], 0, 0, 0);
  }
  float s = 0.f;
#pragma unroll
  for (int nt = 0; nt < 4; ++nt) {
    int c = wc * 64 + nt * 16 + fr;
    float cc = cvec[p * NH + c];
    float ww = w2[c];
#pragma unroll
    for (int mt = 0; mt < 4; ++mt)
#pragma unroll
      for (int i = 0; i < 4; ++i) {
        int r = row0 + wr * 64 + mt * 16 + (lane >> 4) * 4 + i;
        if (r < NN) {
          float x = acc[mt][nt][i] + cc;
          x = fminf(fmaxf(x, -15.f), 15.f);
          float e = __expf(2.f * x);
          s = fmaf((e - 1.f) / (e + 1.f), ww, s);
        }
      }
  }
#pragma unroll
  for (int o = 32; o > 0; o >>= 1) s += __shfl_down(s, o);
  if (lane == 0) wsumf[wave] = s;
  __syncthreads();
  if (tid == 0) atomicAdd(&ssum[p], wsumf[0] + wsumf[1] + wsumf[2] + wsumf[3]);
}

// ---------------- beta (inline per-thread) + beta-scaled W^T (bf16) + bout ----------------

__global__ __launch_bounds__(256) void scaleWtB_kernel(const float* __restrict__ Wgc,
                                                       const float* __restrict__ ssum,
                                                       const float* __restrict__ bgc,
                                                       ushort* __restrict__ Wt,
                                                       float* __restrict__ bout) {
  float m[NP];
  float mx = -1e30f;
#pragma unroll
  for (int p = 0; p < NP; ++p) {
    m[p] = ssum[p] * (1.f / (float)NN);
    mx = fmaxf(mx, m[p]);
  }
  float tot = 0.f;
#pragma unroll
  for (int p = 0; p < NP; ++p) { m[p] = __expf(m[p] - mx); tot += m[p]; }
  float inv = 1.f / tot;
  if (blockIdx.x == 0) {
    int d = threadIdx.x;  // block = 256 = DD
    float s = 0.f;
#pragma unroll
    for (int p = 0; p < NP; ++p) s = fmaf(m[p] * inv, bgc[p * DD + d], s);
    bout[d] = s;
  }
  int i = blockIdx.x * 256 + threadIdx.x;  // over DD * NP * DIN
  if (i < DD * NP * DIN) {
    int n = i >> 10;
    int pk = i & 1023;
    int p = pk >> 8, k = pk & 255;
    Wt[i] = f2bf(m[p] * inv * Wgc[((size_t)p * DIN + k) * DD + n]);
  }
}

// ---------------- gemm_main: out = [g_0|..|g_3] @ Wt^T + bout ----------------
// 128x128 tiles, grid (2 col, 391 row): 782 blocks (~3/CU) fixes the 8.3% occupancy of
// the 391-block acc[4][8] version; staggered staging rows fix the 3-way write conflicts.

__global__ __launch_bounds__(256) void gemm_main(
    const ushort* __restrict__ g, const ushort* __restrict__ Wt,
    const float* __restrict__ bout, float* __restrict__ out) {
  __shared__ ushort As[128 * SA];
  __shared__ ushort Bs[128 * SA];
  const int tid = threadIdx.x;
  const int row0 = blockIdx.y * 128;
  const int col0 = blockIdx.x * 128;
  const int wave = tid >> 6, lane = tid & 63;
  const int wr = wave >> 1, wc = wave & 1;
  const int q = tid >> 2, sseg = tid & 3;
  const int srow = ((q & 31) << 1) | (q >> 5);  // staggered, bijective 0..63
  const int fr = lane & 15, fk = (lane >> 4) * 8;
  int ar0 = row0 + srow; if (ar0 >= NN) ar0 = NN - 1;
  int ar1 = row0 + srow + 64; if (ar1 >= NN) ar1 = NN - 1;
  f32x4 acc[4][4] = {};
  for (int p = 0; p < NP; ++p) {
    const ushort* Ag = g + (size_t)p * NN * DIN;
    for (int k2 = 0; k2 < DIN; k2 += 32) {
      uint4 av0 = *(const uint4*)(Ag + (size_t)ar0 * DIN + k2 + sseg * 8);
      uint4 av1 = *(const uint4*)(Ag + (size_t)ar1 * DIN + k2 + sseg * 8);
      uint4 bv0 = *(const uint4*)(Wt + (size_t)(col0 + srow) * (NP * DIN) + p * DIN + k2 + sseg * 8);
      uint4 bv1 = *(const uint4*)(Wt + (size_t)(col0 + srow + 64) * (NP * DIN) + p * DIN + k2 + sseg * 8);
      __syncthreads();
      *(uint4*)&As[srow * SA + sseg * 8] = av0;
      *(uint4*)&As[(srow + 64) * SA + sseg * 8] = av1;
      *(uint4*)&Bs[srow * SA + sseg * 8] = bv0;
      *(uint4*)&Bs[(srow + 64) * SA + sseg * 8] = bv1;
      __syncthreads();
      bf16x8 af[4], bfv[4];
#pragma unroll
      for (int t = 0; t < 4; ++t) {
        af[t] = *(const bf16x8*)&As[(wr * 64 + t * 16 + fr) * SA + fk];
        bfv[t] = *(const bf16x8*)&Bs[(wc * 64 + t * 16 + fr) * SA + fk];
      }
#pragma unroll
      for (int mt = 0; mt < 4; ++mt)
#pragma unroll
        for (int nt = 0; nt < 4; ++nt)
          acc[mt][nt] = __builtin_amdgcn_mfma_f32_16x16x32_bf16(af[mt], bfv[nt], acc[mt][nt], 0, 0, 0);
    }
  }
#pragma unroll
  for (int nt = 0; nt < 4; ++nt) {
    int c = col0 + wc * 64 + nt * 16 + fr;
    float bb = bout[c];
#pragma unroll
    for (int mt = 0; mt < 4; ++mt)
#pragma unroll
      for (int i = 0; i < 4; ++i) {
        int r = row0 + wr * 64 + mt * 16 + (lane >> 4) * 4 + i;
        if (r < NN) out[(size_t)r * DD + c] = acc[mt][nt][i] + bb;
      }
  }
}

// ---------------- launcher ----------------

extern "C" void kernel_launch(void* const* d_in, const int* in_sizes, int n_in,
                              void* d_out, int out_size, void* d_ws, size_t ws_size,
                              hipStream_t stream) {
  const float* h = (const float*)d_in[0];
  const int* src = (const int*)d_in[1];
  const int* dst = (const int*)d_in[2];
  const float* Wgc = (const float*)d_in[3];
  const float* bgc = (const float*)d_in[4];
  const float* W1 = (const float*)d_in[5];
  const float* b1 = (const float*)d_in[6];
  const float* w2 = (const float*)d_in[7];
  float* out = (float*)d_out;

  char* base = (char*)d_ws;
  size_t off = 0;
  auto alloc = [&](size_t bytes) -> char* {
    char* ptr = base + off;
    off = (off + bytes + 255) & ~(size_t)255;
    return ptr;
  };
  ushort* cntD = (ushort*)alloc((size_t)NP * NSEG * NN * sizeof(ushort));
  ushort* cntS = (ushort*)alloc((size_t)NP * NSEG * NN * sizeof(ushort));
  float* rin = (float*)alloc((size_t)NP * NN * sizeof(float));
  float* rout = (float*)alloc((size_t)NP * NN * sizeof(float));
  int* row_ptr = (int*)alloc((size_t)NP * (NN + 1) * sizeof(int));
  int* chunkdeg = (int*)alloc((size_t)NP * NSC * sizeof(int));
  int* colbuf = (int*)alloc((size_t)NP * NE * sizeof(int));
  ushort* h2 = (ushort*)alloc((size_t)NN * DIN * sizeof(ushort));
  ushort* g = (ushort*)alloc((size_t)NP * NN * DIN * sizeof(ushort));
  ushort* Mt = (ushort*)alloc((size_t)NP * NH * DIN * sizeof(ushort));
  ushort* Wt = (ushort*)alloc((size_t)DD * NP * DIN * sizeof(ushort));
  float* cvec = (float*)alloc((size_t)NP * NH * sizeof(float));
  float* ssum = (float*)alloc(NP * sizeof(float));
  float* bout = (float*)alloc(DD * sizeof(float));
  if (off > ws_size) return;

  hipMemsetAsync(ssum, 0, NP * sizeof(float), stream);

  histX_kernel<<<dim3(NHC * NSEG, NP, 2), 256, 0, stream>>>(src, dst, cntS, cntD);
  scanA_kernel<<<dim3(NSC, NP), 1024, 0, stream>>>(cntD, cntS, rin, rout, row_ptr, chunkdeg);
  rpfin_kernel<<<dim3((NN + 1023) / 1024, NP), 1024, 0, stream>>>(row_ptr, chunkdeg);
  cvt_h_kernel<<<(NN * DIN / 4 + 255) / 256, 256, 0, stream>>>((const float4*)h, (ushort4*)h2);
  scatter_kernel<<<dim3(NHC * NSEG, NP), 256, 0, stream>>>(src, dst, cntD, row_ptr, colbuf);
  agg_kernel<<<dim3(NN / 4, NP), 256, 0, stream>>>(h2, colbuf, row_ptr, rout, rin, g, 0);
  wmulcvec_kernel<<<dim3(DIN + 1, NP), NH, 0, stream>>>(Wgc, bgc, W1, b1, Mt, cvec);
  gemm_sem<<<dim3((NN + 127) / 128, NP), 256, 0, stream>>>(g, Mt, cvec, w2, ssum);
  scaleWtB_kernel<<<(DD * NP * DIN + 255) / 256, 256, 0, stream>>>(Wgc, ssum, bgc, Wt, bout);
  gemm_main<<<dim3(2, (NN + 127) / 128), 256, 0, stream>>>(g, Wt, bout, out);
}